// Round 18
// baseline (2620.523 us; speedup 1.0000x reference)
//
#include <hip/hip_runtime.h>
#include <stdint.h>

typedef _Float16 half8 __attribute__((ext_vector_type(8)));
typedef _Float16 half4 __attribute__((ext_vector_type(4)));
typedef __attribute__((ext_vector_type(8))) short short8;
typedef __attribute__((ext_vector_type(4))) float f32x4;
typedef __attribute__((ext_vector_type(16))) float f32x16;

// ---------- helpers ----------
__device__ __forceinline__ unsigned encf(float x){                // monotonic f32->u32
  uint32_t u = __float_as_uint(x);
  return (u & 0x80000000u) ? ~u : (u | 0x80000000u);
}
__device__ __forceinline__ float decf(unsigned u){
  uint32_t b = (u & 0x80000000u) ? (u & 0x7FFFFFFFu) : ~u;
  return __uint_as_float(b);
}
__device__ __forceinline__ void gload16(const void* g, void* l){
  __builtin_amdgcn_global_load_lds(
      (const __attribute__((address_space(1))) void*)g,
      (__attribute__((address_space(3))) void*)l, 16, 0, 0);
}

// ---------- small utility kernels ----------
__global__ __launch_bounds__(256) void zero_u32(unsigned* __restrict__ p, int n){
  for (int i = blockIdx.x*256 + threadIdx.x; i < n; i += gridDim.x*256) p[i] = 0u;
}

// w (f32, [CO][CI][3][3]) -> wp (fp16, [kc16][tap][co_grp][32co x 16ch]) zero-padded.
// Per (kc,tap,grp) the 1KB region is exactly one wave a-frag (lane-contiguous).
__global__ __launch_bounds__(256) void pack_w(const float* __restrict__ w, _Float16* __restrict__ wp,
                                              int CO, int CI, int COP, int CINP){
  int idx = blockIdx.x*256 + threadIdx.x;
  int total = 9*COP*CINP;
  if (idx >= total) return;
  int ci = idx % CINP;
  int rest = idx / CINP;
  int co = rest % COP;
  int t  = rest / COP;
  float v = 0.f;
  if (co < CO && ci < CI) v = w[((size_t)co*CI + ci)*9 + t];
  int kc = ci >> 4, chl = ci & 15;
  wp[(((size_t)kc*9 + t)*(COP/32) + (co>>5))*512 + (co&31)*16 + chl] = (_Float16)v;
}

__global__ __launch_bounds__(256) void pack_bias(const float* __restrict__ b, float* __restrict__ bp, int n, int npad){
  int i = blockIdx.x*256 + threadIdx.x;
  if (i < npad) bp[i] = (i < n) ? b[i] : 0.f;
}

// features f32 [16][36864] -> rnn_buf (halo 194x194, interior at +1,+1) ch0..15
//                             k1_in (192x192, C=144) ch128..143
// State is NOT copied here: rnn's dual-write puts it in rnn_buf ch16..143 directly.
__global__ __launch_bounds__(256) void pack_feat(const float* __restrict__ f,
                                                 _Float16* __restrict__ rnn_b,
                                                 _Float16* __restrict__ k1_in,
                                                 unsigned fbstr, unsigned rbstr, unsigned kbstr){
  int p = blockIdx.x*256 + threadIdx.x;
  if (p >= 36864) return;
  int b = blockIdx.y;
  int y = p / 192, x = p % 192;
  const float* fb = f + (size_t)b*fbstr;
  _Float16* r = rnn_b + (size_t)b*rbstr + ((size_t)(y+1)*194 + (x+1))*144;
  _Float16* k = k1_in + (size_t)b*kbstr + (size_t)p*144;
  #pragma unroll
  for (int c = 0; c < 16; ++c){
    _Float16 v = (_Float16)fb[c*36864 + p];
    r[c] = v;
    k[128 + c] = v;
  }
}

// ---------- conv3x3: 32x32x16-MFMA implicit GEMM (r17 + T4 counted-vmcnt barrier) ----------
// block = 128 threads = 2 waves.
//  !K3: waves split CO; block = 128co x 4rows x 32px; grid z = batch. DUAL (rnn):
//       epilogue also writes output into next step's rnn halo ch16..143 (ping-pong).
//   K3: waves split ROWS; block = 64co x 8rows x 32px; co-slice of 7 (COP=448);
//       X pre-offset (7,7): only the 172x172 apply-window. Tail: ticket atomic —
//       last block updates st (running max + scale) and resets slot (folds the old
//       update_max launch into k3).
// T4 (round-18): the in-loop barrier is `s_waitcnt vmcnt(6); s_barrier` instead of
// __syncthreads' vmcnt(0) drain. Queue order per kc = [stage loads][18 wreg refills];
// vmcnt(6) retires the stage (LDS visibility) while keeping the 6 newest loads — the
// depth-3 prefetches for next-kc taps 0..2 — in flight across the barrier.
// Weights [kc16][tap][grp][32co x 16ch] flat; depth-3 rotated register pipeline.
// Acts: LDS dbuf [rowS][col34][half2x8ch], staged via global_load_lds.
// OOB-ish stage reads land in allocation slack and only feed store-masked dead outputs.
template<int CINP, bool RELU, bool K3, bool DUAL>
__global__ __launch_bounds__(128, 2) void conv3(
    const _Float16* __restrict__ X, int Wst, unsigned xbstr,
    const _Float16* __restrict__ Wp, int COP,
    const float* __restrict__ bias,
    _Float16* __restrict__ Y, int Wst_out, int DCP, unsigned ybstr,
    _Float16* __restrict__ Y2, unsigned y2str,
    unsigned* __restrict__ slot, float* __restrict__ stt, unsigned* __restrict__ ticket,
    int step, int Ho, int Wo, int nco)
{
  constexpr int KC    = CINP/16;
  constexpr int SROWS = K3 ? 10 : 6;
  constexpr int ITEMS = SROWS*34*2;            // 16B items per buffer (680 / 408)
  constexpr int NRND  = (ITEMS + 127)/128;
  __shared__ _Float16 lds[2][ITEMS*8];

  const int tid  = threadIdx.x;
  const int lane = tid & 63;
  const int wid  = tid >> 6;                   // !K3: co half | K3: row half
  const int l31  = lane & 31;
  const int hsel = lane >> 5;
  const int xb   = blockIdx.x * 32;
  const int yb   = blockIdx.y * (K3 ? 8 : 4);
  const int co_blk = blockIdx.z % nco;
  const int b      = blockIdx.z / nco;

  const _Float16* Xb = X + (size_t)b * xbstr;
  const int NG = COP/32;
  const size_t wtap = (size_t)NG*512;
  const _Float16* wbase = Wp
      + ((size_t)(K3 ? (co_blk*2) : (co_blk*4 + wid*2)))*512 + l31*16 + hsel*8;

  // stage addresses: ITEMS 16B items = [row SROWS][col34][half2]
  uint32_t goff[NRND];
  #pragma unroll
  for (int k = 0; k < NRND; ++k){
    int item = k*128 + tid;
    if (item < ITEMS){
      int row  = item / 68;
      int rem  = item % 68;
      int col  = rem >> 1;
      int half = rem & 1;
      int pix  = (yb + row)*Wst + xb + col;
      goff[k] = (uint32_t)(((uint32_t)pix*CINP + half*8) * 2);   // bytes (kc adds kc*32B)
    } else goff[k] = 0;
  }

  auto stage = [&](int buf, int kc){
    const char* xp = (const char*)Xb + (size_t)kc*32;            // +16 channels
    char* lb = (char*)&lds[buf][0];
    #pragma unroll
    for (int k = 0; k < NRND; ++k){
      if (k*128 + tid < ITEMS)
        gload16(xp + goff[k], lb + k*2048 + wid*1024);
    }
  };

  // b-frag element offsets: boffe[n] + (ky*34 + kx)*16
  uint32_t boffe[4];
  #pragma unroll
  for (int n = 0; n < 4; ++n){
    const int row = K3 ? (wid*4 + n) : n;
    boffe[n] = (uint32_t)((row*34 + l31)*16 + hsel*8);
  }

  f32x16 acc[4][2] = {};
  half8 wreg[3][2];
  // prologue: taps 0,1,2 -> slots 0,1,2 (issued BEFORE stage(0): in-order vmcnt)
  #pragma unroll
  for (int s3 = 0; s3 < 3; ++s3)
    #pragma unroll
    for (int g = 0; g < 2; ++g)
      wreg[s3][g] = *reinterpret_cast<const half8*>(wbase + (size_t)s3*wtap + g*512);

  stage(0, 0);
  __syncthreads();
  for (int kc = 0; kc < KC; ++kc){
    if (kc + 1 < KC) stage((kc+1)&1, kc+1);
    const _Float16* wt = wbase + (size_t)(kc*9)*wtap;
    const _Float16* lb = &lds[kc&1][0];
    half8 breg[2][4];
    #pragma unroll
    for (int n = 0; n < 4; ++n)
      breg[0][n] = *reinterpret_cast<const half8*>(lb + boffe[n]);
    #pragma unroll
    for (int t = 0; t < 9; ++t){
      const int cur = t & 1, nxt = cur ^ 1;
      if (t < 8){
        const int ky1 = (t+1)/3, kx1 = (t+1) - ky1*3;
        #pragma unroll
        for (int n = 0; n < 4; ++n)
          breg[nxt][n] = *reinterpret_cast<const half8*>(lb + boffe[n] + (ky1*34 + kx1)*16);
      }
      #pragma unroll
      for (int n = 0; n < 4; ++n)
        #pragma unroll
        for (int g = 0; g < 2; ++g)
          acc[n][g] = __builtin_amdgcn_mfma_f32_32x32x16_f16(
              wreg[t % 3][g], breg[cur][n], acc[n][g], 0, 0, 0);
      // refill slot t%3 with tap kc*9+t+3 (t>=6 prefetches next kc; tail -> WSLACK)
      #pragma unroll
      for (int g = 0; g < 2; ++g)
        wreg[t % 3][g] = *reinterpret_cast<const half8*>(wt + (size_t)(t+3)*wtap + g*512);
    }
    if (kc + 1 < KC){
      // T4: retire the stage (6 newest loads = next-kc tap 0..2 wreg prefetches stay
      // in flight); raw barrier. memory clobber pins all LDS/global accesses.
      asm volatile("s_waitcnt vmcnt(6)\n\ts_barrier" ::: "memory");
    }
  }

  // ---- epilogue ----
  // C/D: px = xb + l31; co = cobase + g*32 + 4*hsel + 8*q + j (reg = q*4+j)
  const int x = xb + l31;
  float lmax = -3.0e38f;
  #pragma unroll
  for (int n = 0; n < 4; ++n){
    const int y = yb + (K3 ? (wid*4 + n) : n);
    if (y < Ho && x < Wo){
      #pragma unroll
      for (int g = 0; g < 2; ++g){
        #pragma unroll
        for (int q = 0; q < 4; ++q){
          const int cb = (K3 ? (co_blk*64 + g*32) : ((wid*2 + g)*32))
                         + 4*hsel + 8*q;                       // 4 consecutive couts
          f32x4 bs = *reinterpret_cast<const f32x4*>(bias + cb);
          float v[4];
          #pragma unroll
          for (int j = 0; j < 4; ++j){
            float tv = acc[n][g][q*4 + j] + bs[j];
            if (RELU) tv = tv > 0.f ? tv : 0.01f*tv;
            v[j] = tv;
          }
          if constexpr (!K3){
            half4 pk;
            #pragma unroll
            for (int j = 0; j < 4; ++j) pk[j] = (_Float16)v[j];
            *reinterpret_cast<half4*>(Y + (size_t)b*ybstr + ((size_t)y*Wst_out + x)*DCP + cb) = pk;
            if constexpr (DUAL)
              *reinterpret_cast<half4*>(Y2 + (size_t)b*y2str
                  + ((size_t)(y+1)*194 + (x+1))*144 + 16 + cb) = pk;
          } else {
            _Float16* yp = Y + (size_t)b*ybstr;
            #pragma unroll
            for (int j = 0; j < 4; ++j){
              if (cb + j < 441){
                yp[(size_t)(cb+j)*29584 + (size_t)y*172 + x] = (_Float16)v[j];
                lmax = fmaxf(lmax, v[j]);
              }
            }
          }
        }
      }
    }
  }
  if constexpr (K3){
    #pragma unroll
    for (int o = 32; o > 0; o >>= 1) lmax = fmaxf(lmax, __shfl_xor(lmax, o));
    if (lane == 0) atomicMax(slot + b, encf(lmax));
    __syncthreads();                          // both waves' atomicMax issued
    if (tid == 0){
      __threadfence();
      unsigned total = gridDim.x * gridDim.y * gridDim.z;
      unsigned prev = atomicAdd(ticket, 1u);
      if (prev == total - 1u){                // last block: fold update_max
        #pragma unroll
        for (int b2 = 0; b2 < 2; ++b2){
          float nm   = decf(slot[b2]);
          float oldM = stt[2*b2];
          float M    = (step == 0) ? nm : fmaxf(oldM, nm);
          stt[2*b2+1] = (step == 0) ? 0.f : expf(oldM - M);
          stt[2*b2]   = M;
          slot[b2] = 0u;
        }
        __threadfence();
        *ticket = 0u;
      }
    }
  }
}

// per-pixel: w_t = exp(k3[t][y][x]-M); unnorm = unnorm*scale + sum_t w_t*rad
__global__ __launch_bounds__(256) void apply_acc(
    const _Float16* __restrict__ k3out, const float* __restrict__ rad,
    const float* __restrict__ st,
    float* __restrict__ unnorm, float* __restrict__ sumw)
{
  const int tx = threadIdx.x & 63, ty = threadIdx.x >> 6;
  const int x = blockIdx.x*64 + tx;
  const int y = blockIdx.y*4 + ty;
  const int b = blockIdx.z;
  if (x >= 172 || y >= 172) return;
  const float M = st[2*b], scale = st[2*b+1];
  const _Float16* kp = k3out + (size_t)b*13046544 + (size_t)y*172 + x;   // 441*29584
  const float* rb = rad + (size_t)b*884736;          // 8*3*36864
  float a0 = 0.f, a1 = 0.f, a2 = 0.f, aw = 0.f;
  for (int dy = 0; dy < 21; ++dy){
    const float* r0 = rb + (size_t)(y+dy)*192 + x;
    #pragma unroll
    for (int dx = 0; dx < 21; ++dx){
      float w = __expf((float)kp[(size_t)(dy*21+dx)*29584] - M);
      aw += w;
      a0 += w * r0[dx];
      a1 += w * r0[36864 + dx];
      a2 += w * r0[73728 + dx];
    }
  }
  size_t p = (size_t)b*88752 + (size_t)y*172 + x;
  size_t ps = (size_t)b*29584 + (size_t)y*172 + x;
  unnorm[p]        = unnorm[p]*scale        + a0;
  unnorm[p+29584]  = unnorm[p+29584]*scale  + a1;
  unnorm[p+59168]  = unnorm[p+59168]*scale  + a2;
  sumw[ps]         = sumw[ps]*scale         + aw;
}

__global__ __launch_bounds__(256) void finalize_out(const float* __restrict__ unnorm,
                                                    const float* __restrict__ sumw,
                                                    float* __restrict__ out){
  int i = blockIdx.x*256 + threadIdx.x;
  int b = blockIdx.y;
  if (i >= 88752) return;
  int p = i % 29584;
  out[(size_t)b*88752 + i] = unnorm[(size_t)b*88752 + i] / (sumw[(size_t)b*29584 + p] + 1e-8f);
}

// ---------- host ----------
extern "C" void kernel_launch(void* const* d_in, const int* in_sizes, int n_in,
                              void* d_out, int out_size, void* d_ws, size_t ws_size,
                              hipStream_t stream) {
  const float* features = (const float*)d_in[0];
  const float* radiance = (const float*)d_in[1];
  const float* w_rnn = (const float*)d_in[2];
  const float* b_rnn = (const float*)d_in[3];
  const float* w_k1  = (const float*)d_in[4];
  const float* b_k1  = (const float*)d_in[5];
  const float* w_k2  = (const float*)d_in[6];
  const float* b_k2  = (const float*)d_in[7];
  const float* w_k3  = (const float*)d_in[8];
  const float* b_k3  = (const float*)d_in[9];
  float* out = (float*)d_out;

  char* ws = (char*)d_ws;
  size_t off = 0;
  auto alloc = [&](size_t bytes)->char*{
    char* p = ws + off;
    off = (off + bytes + 255) & ~(size_t)255;
    return p;
  };
  const size_t WSLACK = 98304;   // depth-3 pipeline tail over-read slack
  _Float16* wp_rnn   = (_Float16*)alloc((size_t)9*128*144*2 + WSLACK);
  _Float16* wp_k1    = (_Float16*)alloc((size_t)9*128*144*2 + WSLACK);
  _Float16* wp_k2    = (_Float16*)alloc((size_t)9*128*128*2 + WSLACK);
  _Float16* wp_k3    = (_Float16*)alloc((size_t)9*448*128*2 + WSLACK);
  float*    bias_k3p = (float*)   alloc((size_t)448*4);
  // per-batch strides (elements)
  const unsigned RB  = 194u*194u*144u;             // rnn_in halo (C=144), x2 ping-pong
  const unsigned KB  = (192u*192u+64u)*144u;       // k1_in (C=144, +slack)
  const unsigned K2B = (194u*190u+64u)*128u;       // k2_in
  const unsigned K3B = (194u*188u+64u)*128u;       // k3_in
  const unsigned KOB = 441u*29584u;                // k3_out (172x172 window planes)
  _Float16* rnn_inA = (_Float16*)alloc((size_t)2*RB*2);
  _Float16* rnn_inB = (_Float16*)alloc((size_t)2*RB*2);
  _Float16* k1_in  = (_Float16*)alloc((size_t)2*KB*2);
  _Float16* k2_in  = (_Float16*)alloc((size_t)2*K2B*2);
  _Float16* k3_in  = (_Float16*)alloc((size_t)2*K3B*2);
  _Float16* k3_out = (_Float16*)alloc((size_t)2*KOB*2);
  float*    accz   = (float*)   alloc((size_t)236680*4);
  if (off > ws_size) return;  // workspace too small -> fail loudly (no OOB writes)

  float*    unnorm = accz;                 // [2][3][172][172]
  float*    sumw   = accz + 177504;        // [2][172][172]
  float*    st     = accz + 236672;        // [2][{M,scale}]
  unsigned* slot   = (unsigned*)(accz + 236676);  // [2]
  unsigned* ticket = (unsigned*)(accz + 236678);  // [1]

  _Float16* rnn_buf[2] = { rnn_inA, rnn_inB };

  // weight prepack (pure function of inputs; runs every call)
  pack_w<<<(9*128*144+255)/256, 256, 0, stream>>>(w_rnn, wp_rnn, 128, 144, 128, 144);
  pack_w<<<(9*128*144+255)/256, 256, 0, stream>>>(w_k1,  wp_k1,  128, 144, 128, 144);
  pack_w<<<(9*128*128+255)/256, 256, 0, stream>>>(w_k2,  wp_k2,  128, 128, 128, 128);
  pack_w<<<(9*448*128+255)/256, 256, 0, stream>>>(w_k3,  wp_k3,  441, 128, 448, 128);
  pack_bias<<<2, 256, 0, stream>>>(b_k3, bias_k3p, 441, 448);

  // zero both rnn ping-pong buffers (halo borders + step-0 state) and accumulators
  zero_u32<<<2048, 256, 0, stream>>>((unsigned*)rnn_inA, (int)RB);   // RB u32 words = 2*RB elem
  zero_u32<<<2048, 256, 0, stream>>>((unsigned*)rnn_inB, (int)RB);
  zero_u32<<<925,  256, 0, stream>>>((unsigned*)accz, 236680);

  for (int s = 0; s < 8; ++s){
    const float* f   = features + (size_t)s*16*36864;   // batch stride 8*16*36864
    const float* rad = radiance + (size_t)s*3*36864;    // batch stride 8*3*36864
    _Float16* rcur = rnn_buf[s & 1];
    _Float16* rnxt = rnn_buf[(s + 1) & 1];
    // features -> rcur ch0..15 (interior) and k1_in ch128..143 (state arrives via DUAL)
    pack_feat<<<dim3(144,2), 256, 0, stream>>>(f, rcur, k1_in,
                                               8u*16u*36864u, RB, KB);
    // rnn: 144->128 SAME via zero halo, lrelu; -> k1_in ch0..127 AND rnxt halo ch16..143
    conv3<144,true ,false,true ><<<dim3(6,48,2), 128, 0, stream>>>(
        rcur, 194, RB, wp_rnn, 128, b_rnn, k1_in, 192, 144, KB,
        rnxt, RB, nullptr, nullptr, nullptr, 0, 192, 192, 1);
    // k1: 144->128 VALID, lrelu; only window [7,185) (178^2) -> k2_in at (7,7)
    conv3<144,true ,false,false><<<dim3(6,45,2), 128, 0, stream>>>(
        k1_in + (size_t)(7*192 + 7)*144, 192, KB, wp_k1, 128, b_k1,
        k2_in + (size_t)(7*190 + 7)*128, 190, 128, K2B,
        nullptr, 0, nullptr, nullptr, nullptr, 0, 178, 178, 1);
    // k2: 128->128 VALID, lrelu; only window [7,181) (174^2) -> k3_in at (7,7)
    conv3<128,true ,false,false><<<dim3(6,44,2), 128, 0, stream>>>(
        k2_in + (size_t)(7*190 + 7)*128, 190, K2B, wp_k2, 128, b_k2,
        k3_in + (size_t)(7*188 + 7)*128, 188, 128, K3B,
        nullptr, 0, nullptr, nullptr, nullptr, 0, 174, 174, 1);
    // k3: 128->441(448 pad, 7 co-slices of 64) VALID, no relu; 172x172 window;
    // tail folds the running-max update (ticket: last block updates st, resets slot)
    conv3<128,false,true ,false><<<dim3(6,22,14), 128, 0, stream>>>(
        k3_in + (size_t)(7*188 + 7)*128, 188, K3B, wp_k3, 448, bias_k3p,
        k3_out, 0, 0, KOB, nullptr, 0, slot, st, ticket, s, 172, 172, 7);
    apply_acc<<<dim3(3,43,2), 256, 0, stream>>>(k3_out, rad, st, unnorm, sumw);
  }
  finalize_out<<<dim3(347,2), 256, 0, stream>>>(unnorm, sumw, out);
}

// Round 19
// 2239.056 us; speedup vs baseline: 1.1704x; 1.1704x over previous
//
#include <hip/hip_runtime.h>
#include <stdint.h>

typedef _Float16 half8 __attribute__((ext_vector_type(8)));
typedef _Float16 half4 __attribute__((ext_vector_type(4)));
typedef __attribute__((ext_vector_type(8))) short short8;
typedef __attribute__((ext_vector_type(4))) float f32x4;
typedef __attribute__((ext_vector_type(16))) float f32x16;

// ---------- helpers ----------
__device__ __forceinline__ unsigned encf(float x){                // monotonic f32->u32
  uint32_t u = __float_as_uint(x);
  return (u & 0x80000000u) ? ~u : (u | 0x80000000u);
}
__device__ __forceinline__ float decf(unsigned u){
  uint32_t b = (u & 0x80000000u) ? (u & 0x7FFFFFFFu) : ~u;
  return __uint_as_float(b);
}
__device__ __forceinline__ void gload16(const void* g, void* l){
  __builtin_amdgcn_global_load_lds(
      (const __attribute__((address_space(1))) void*)g,
      (__attribute__((address_space(3))) void*)l, 16, 0, 0);
}

// ---------- small utility kernels ----------
__global__ __launch_bounds__(256) void zero_u32(unsigned* __restrict__ p, int n){
  for (int i = blockIdx.x*256 + threadIdx.x; i < n; i += gridDim.x*256) p[i] = 0u;
}

// w (f32, [CO][CI][3][3]) -> wp (fp16, [kc16][tap][co_grp][32co x 16ch]) zero-padded.
// Per (kc,tap,grp) the 1KB region is exactly one wave a-frag (lane-contiguous).
__global__ __launch_bounds__(256) void pack_w(const float* __restrict__ w, _Float16* __restrict__ wp,
                                              int CO, int CI, int COP, int CINP){
  int idx = blockIdx.x*256 + threadIdx.x;
  int total = 9*COP*CINP;
  if (idx >= total) return;
  int ci = idx % CINP;
  int rest = idx / CINP;
  int co = rest % COP;
  int t  = rest / COP;
  float v = 0.f;
  if (co < CO && ci < CI) v = w[((size_t)co*CI + ci)*9 + t];
  int kc = ci >> 4, chl = ci & 15;
  wp[(((size_t)kc*9 + t)*(COP/32) + (co>>5))*512 + (co&31)*16 + chl] = (_Float16)v;
}

__global__ __launch_bounds__(256) void pack_bias(const float* __restrict__ b, float* __restrict__ bp, int n, int npad){
  int i = blockIdx.x*256 + threadIdx.x;
  if (i < npad) bp[i] = (i < n) ? b[i] : 0.f;
}

// features f32 [16][36864] -> rnn_buf (halo 194x194, interior at +1,+1) ch0..15
//                             k1_in (192x192, C=144) ch128..143
// State is NOT copied here: rnn's dual-write puts it in rnn_buf ch16..143 directly.
__global__ __launch_bounds__(256) void pack_feat(const float* __restrict__ f,
                                                 _Float16* __restrict__ rnn_b,
                                                 _Float16* __restrict__ k1_in,
                                                 unsigned fbstr, unsigned rbstr, unsigned kbstr){
  int p = blockIdx.x*256 + threadIdx.x;
  if (p >= 36864) return;
  int b = blockIdx.y;
  int y = p / 192, x = p % 192;
  const float* fb = f + (size_t)b*fbstr;
  _Float16* r = rnn_b + (size_t)b*rbstr + ((size_t)(y+1)*194 + (x+1))*144;
  _Float16* k = k1_in + (size_t)b*kbstr + (size_t)p*144;
  #pragma unroll
  for (int c = 0; c < 16; ++c){
    _Float16 v = (_Float16)fb[c*36864 + p];
    r[c] = v;
    k[128 + c] = v;
  }
}

// ---------- conv3x3: 32x32x16-MFMA implicit GEMM (r17 core + co-split small convs) ----------
// block = 128 threads = 2 waves.
//  !K3,!RS (legacy): waves split CO (wid=co half); block = 128co x 4rows x 32px.
//  RS (round-19, small convs): waves split ROWS (wid=row half: rows yb+2wid..+1, N=2);
//      both waves the SAME 64-co slice (co_blk of nco=2, G=2) -> grid doubles to
//      1152 blocks (4.5/CU) and __launch_bounds__(128,3) lifts residency (small convs
//      were 2.25 blocks/CU grid-limited). DUAL (rnn): epilogue also writes output into
//      next step's rnn halo ch16..143 (ping-pong buffers).
//   K3: waves split ROWS (8-row blocks, N=4); 64-co slice of 7 (COP=448); X pre-offset
//      (7,7): only the 172x172 apply-window is computed.
// Per-wave per tap: G=2 a-frags (2KB weights, L1-hot), N ds_read_b128, 2N MFMA.
// Weights [kc16][tap][grp][32co x 16ch] flat; depth-3 rotated register pipeline
// (slot=t%3, prologue pre-stage before stage(0): in-order-vmcnt clean; t>=6 refills
// prefetch next kc across the barrier). Acts: LDS dbuf [rowS][col34][half2x8ch],
// staged via global_load_lds. OOB-ish stage reads land in allocation slack and only
// feed store-masked dead outputs.
template<int CINP, bool RELU, bool K3, bool DUAL, bool RS, int MINW>
__global__ __launch_bounds__(128, MINW) void conv3(
    const _Float16* __restrict__ X, int Wst, unsigned xbstr,
    const _Float16* __restrict__ Wp, int COP,
    const float* __restrict__ bias,
    _Float16* __restrict__ Y, int Wst_out, int DCP, unsigned ybstr,
    _Float16* __restrict__ Y2, unsigned y2str,
    unsigned* __restrict__ slot, int Ho, int Wo,
    int nco)
{
  constexpr int KC    = CINP/16;
  constexpr int NW    = K3 ? 4 : (RS ? 2 : 4);   // rows per wave
  constexpr int BROWS = K3 ? 8 : 4;              // rows per block
  constexpr int SROWS = BROWS + 2;
  constexpr int ITEMS = SROWS*34*2;              // 16B items per buffer
  constexpr int NRND  = (ITEMS + 127)/128;
  __shared__ _Float16 lds[2][ITEMS*8];

  const int tid  = threadIdx.x;
  const int lane = tid & 63;
  const int wid  = tid >> 6;                   // (K3||RS): row half | else: co half
  const int l31  = lane & 31;
  const int hsel = lane >> 5;
  const int xb   = blockIdx.x * 32;
  const int yb   = blockIdx.y * BROWS;
  const int co_blk = blockIdx.z % nco;
  const int b      = blockIdx.z / nco;

  const _Float16* Xb = X + (size_t)b * xbstr;
  const int NG = COP/32;
  const size_t wtap = (size_t)NG*512;
  const _Float16* wbase = Wp
      + ((size_t)((K3 || RS) ? (co_blk*2) : (co_blk*4 + wid*2)))*512 + l31*16 + hsel*8;

  // stage addresses: ITEMS 16B items = [row SROWS][col34][half2]
  uint32_t goff[NRND];
  #pragma unroll
  for (int k = 0; k < NRND; ++k){
    int item = k*128 + tid;
    if (item < ITEMS){
      int row  = item / 68;
      int rem  = item % 68;
      int col  = rem >> 1;
      int half = rem & 1;
      int pix  = (yb + row)*Wst + xb + col;
      goff[k] = (uint32_t)(((uint32_t)pix*CINP + half*8) * 2);   // bytes (kc adds kc*32B)
    } else goff[k] = 0;
  }

  auto stage = [&](int buf, int kc){
    const char* xp = (const char*)Xb + (size_t)kc*32;            // +16 channels
    char* lb = (char*)&lds[buf][0];
    #pragma unroll
    for (int k = 0; k < NRND; ++k){
      if (k*128 + tid < ITEMS)
        gload16(xp + goff[k], lb + k*2048 + wid*1024);
    }
  };

  // b-frag element offsets: boffe[n] + (ky*34 + kx)*16
  uint32_t boffe[NW];
  #pragma unroll
  for (int n = 0; n < NW; ++n){
    const int row = K3 ? (wid*4 + n) : (RS ? (wid*2 + n) : n);
    boffe[n] = (uint32_t)((row*34 + l31)*16 + hsel*8);
  }

  f32x16 acc[NW][2] = {};
  half8 wreg[3][2];
  // prologue: taps 0,1,2 -> slots 0,1,2 (issued BEFORE stage(0): in-order vmcnt)
  #pragma unroll
  for (int s3 = 0; s3 < 3; ++s3)
    #pragma unroll
    for (int g = 0; g < 2; ++g)
      wreg[s3][g] = *reinterpret_cast<const half8*>(wbase + (size_t)s3*wtap + g*512);

  stage(0, 0);
  __syncthreads();
  for (int kc = 0; kc < KC; ++kc){
    if (kc + 1 < KC) stage((kc+1)&1, kc+1);
    const _Float16* wt = wbase + (size_t)(kc*9)*wtap;
    const _Float16* lb = &lds[kc&1][0];
    half8 breg[2][NW];
    #pragma unroll
    for (int n = 0; n < NW; ++n)
      breg[0][n] = *reinterpret_cast<const half8*>(lb + boffe[n]);
    #pragma unroll
    for (int t = 0; t < 9; ++t){
      const int cur = t & 1, nxt = cur ^ 1;
      if (t < 8){
        const int ky1 = (t+1)/3, kx1 = (t+1) - ky1*3;
        #pragma unroll
        for (int n = 0; n < NW; ++n)
          breg[nxt][n] = *reinterpret_cast<const half8*>(lb + boffe[n] + (ky1*34 + kx1)*16);
      }
      #pragma unroll
      for (int n = 0; n < NW; ++n)
        #pragma unroll
        for (int g = 0; g < 2; ++g)
          acc[n][g] = __builtin_amdgcn_mfma_f32_32x32x16_f16(
              wreg[t % 3][g], breg[cur][n], acc[n][g], 0, 0, 0);
      // refill slot t%3 with tap kc*9+t+3 (t>=6 prefetches next kc; tail -> WSLACK)
      #pragma unroll
      for (int g = 0; g < 2; ++g)
        wreg[t % 3][g] = *reinterpret_cast<const half8*>(wt + (size_t)(t+3)*wtap + g*512);
    }
    if (kc + 1 < KC) __syncthreads();
  }

  // ---- epilogue ----
  // C/D: px = xb + l31; co = cobase + g*32 + 4*hsel + 8*q + j (reg = q*4+j)
  const int x = xb + l31;
  float lmax = -3.0e38f;
  #pragma unroll
  for (int n = 0; n < NW; ++n){
    const int y = yb + (K3 ? (wid*4 + n) : (RS ? (wid*2 + n) : n));
    if (y < Ho && x < Wo){
      #pragma unroll
      for (int g = 0; g < 2; ++g){
        #pragma unroll
        for (int q = 0; q < 4; ++q){
          const int cb = ((K3 || RS) ? (co_blk*64 + g*32) : ((wid*2 + g)*32))
                         + 4*hsel + 8*q;                       // 4 consecutive couts
          f32x4 bs = *reinterpret_cast<const f32x4*>(bias + cb);
          float v[4];
          #pragma unroll
          for (int j = 0; j < 4; ++j){
            float tv = acc[n][g][q*4 + j] + bs[j];
            if (RELU) tv = tv > 0.f ? tv : 0.01f*tv;
            v[j] = tv;
          }
          if constexpr (!K3){
            half4 pk;
            #pragma unroll
            for (int j = 0; j < 4; ++j) pk[j] = (_Float16)v[j];
            *reinterpret_cast<half4*>(Y + (size_t)b*ybstr + ((size_t)y*Wst_out + x)*DCP + cb) = pk;
            if constexpr (DUAL)
              *reinterpret_cast<half4*>(Y2 + (size_t)b*y2str
                  + ((size_t)(y+1)*194 + (x+1))*144 + 16 + cb) = pk;
          } else {
            _Float16* yp = Y + (size_t)b*ybstr;
            #pragma unroll
            for (int j = 0; j < 4; ++j){
              if (cb + j < 441){
                yp[(size_t)(cb+j)*29584 + (size_t)y*172 + x] = (_Float16)v[j];
                lmax = fmaxf(lmax, v[j]);
              }
            }
          }
        }
      }
    }
  }
  if constexpr (K3){
    #pragma unroll
    for (int o = 32; o > 0; o >>= 1) lmax = fmaxf(lmax, __shfl_xor(lmax, o));
    if (lane == 0) atomicMax(slot + b, encf(lmax));
  }
}

// streaming-max state update per batch: st[2b]=M, st[2b+1]=scale; resets slot
__global__ void update_max(float* __restrict__ st, unsigned* __restrict__ slot, int step){
  int b = threadIdx.x;
  if (b < 2){
    float nm   = decf(slot[b]);
    float oldM = st[2*b];
    float M    = (step == 0) ? nm : fmaxf(oldM, nm);
    st[2*b+1] = (step == 0) ? 0.f : expf(oldM - M);
    st[2*b]   = M;
    slot[b] = 0u;
  }
}

// per-pixel: w_t = exp(k3[t][y][x]-M); unnorm = unnorm*scale + sum_t w_t*rad
__global__ __launch_bounds__(256) void apply_acc(
    const _Float16* __restrict__ k3out, const float* __restrict__ rad,
    const float* __restrict__ st,
    float* __restrict__ unnorm, float* __restrict__ sumw)
{
  const int tx = threadIdx.x & 63, ty = threadIdx.x >> 6;
  const int x = blockIdx.x*64 + tx;
  const int y = blockIdx.y*4 + ty;
  const int b = blockIdx.z;
  if (x >= 172 || y >= 172) return;
  const float M = st[2*b], scale = st[2*b+1];
  const _Float16* kp = k3out + (size_t)b*13046544 + (size_t)y*172 + x;   // 441*29584
  const float* rb = rad + (size_t)b*884736;          // 8*3*36864
  float a0 = 0.f, a1 = 0.f, a2 = 0.f, aw = 0.f;
  for (int dy = 0; dy < 21; ++dy){
    const float* r0 = rb + (size_t)(y+dy)*192 + x;
    #pragma unroll
    for (int dx = 0; dx < 21; ++dx){
      float w = __expf((float)kp[(size_t)(dy*21+dx)*29584] - M);
      aw += w;
      a0 += w * r0[dx];
      a1 += w * r0[36864 + dx];
      a2 += w * r0[73728 + dx];
    }
  }
  size_t p = (size_t)b*88752 + (size_t)y*172 + x;
  size_t ps = (size_t)b*29584 + (size_t)y*172 + x;
  unnorm[p]        = unnorm[p]*scale        + a0;
  unnorm[p+29584]  = unnorm[p+29584]*scale  + a1;
  unnorm[p+59168]  = unnorm[p+59168]*scale  + a2;
  sumw[ps]         = sumw[ps]*scale         + aw;
}

__global__ __launch_bounds__(256) void finalize_out(const float* __restrict__ unnorm,
                                                    const float* __restrict__ sumw,
                                                    float* __restrict__ out){
  int i = blockIdx.x*256 + threadIdx.x;
  int b = blockIdx.y;
  if (i >= 88752) return;
  int p = i % 29584;
  out[(size_t)b*88752 + i] = unnorm[(size_t)b*88752 + i] / (sumw[(size_t)b*29584 + p] + 1e-8f);
}

// ---------- host ----------
extern "C" void kernel_launch(void* const* d_in, const int* in_sizes, int n_in,
                              void* d_out, int out_size, void* d_ws, size_t ws_size,
                              hipStream_t stream) {
  const float* features = (const float*)d_in[0];
  const float* radiance = (const float*)d_in[1];
  const float* w_rnn = (const float*)d_in[2];
  const float* b_rnn = (const float*)d_in[3];
  const float* w_k1  = (const float*)d_in[4];
  const float* b_k1  = (const float*)d_in[5];
  const float* w_k2  = (const float*)d_in[6];
  const float* b_k2  = (const float*)d_in[7];
  const float* w_k3  = (const float*)d_in[8];
  const float* b_k3  = (const float*)d_in[9];
  float* out = (float*)d_out;

  char* ws = (char*)d_ws;
  size_t off = 0;
  auto alloc = [&](size_t bytes)->char*{
    char* p = ws + off;
    off = (off + bytes + 255) & ~(size_t)255;
    return p;
  };
  const size_t WSLACK = 98304;   // depth-3 pipeline tail over-read slack
  _Float16* wp_rnn   = (_Float16*)alloc((size_t)9*128*144*2 + WSLACK);
  _Float16* wp_k1    = (_Float16*)alloc((size_t)9*128*144*2 + WSLACK);
  _Float16* wp_k2    = (_Float16*)alloc((size_t)9*128*128*2 + WSLACK);
  _Float16* wp_k3    = (_Float16*)alloc((size_t)9*448*128*2 + WSLACK);
  float*    bias_k3p = (float*)   alloc((size_t)448*4);
  // per-batch strides (elements)
  const unsigned RB  = 194u*194u*144u;             // rnn_in halo (C=144), x2 ping-pong
  const unsigned KB  = (192u*192u+64u)*144u;       // k1_in (C=144, +slack)
  const unsigned K2B = (194u*190u+64u)*128u;       // k2_in
  const unsigned K3B = (194u*188u+64u)*128u;       // k3_in
  const unsigned KOB = 441u*29584u;                // k3_out (172x172 window planes)
  _Float16* rnn_inA = (_Float16*)alloc((size_t)2*RB*2);
  _Float16* rnn_inB = (_Float16*)alloc((size_t)2*RB*2);
  _Float16* k1_in  = (_Float16*)alloc((size_t)2*KB*2);
  _Float16* k2_in  = (_Float16*)alloc((size_t)2*K2B*2);
  _Float16* k3_in  = (_Float16*)alloc((size_t)2*K3B*2);
  _Float16* k3_out = (_Float16*)alloc((size_t)2*KOB*2);
  float*    accz   = (float*)   alloc((size_t)236678*4);
  if (off > ws_size) return;  // workspace too small -> fail loudly (no OOB writes)

  float*    unnorm = accz;                 // [2][3][172][172]
  float*    sumw   = accz + 177504;        // [2][172][172]
  float*    st     = accz + 236672;        // [2][{M,scale}]
  unsigned* slot   = (unsigned*)(accz + 236676);  // [2]

  _Float16* rnn_buf[2] = { rnn_inA, rnn_inB };

  // weight prepack (pure function of inputs; runs every call)
  pack_w<<<(9*128*144+255)/256, 256, 0, stream>>>(w_rnn, wp_rnn, 128, 144, 128, 144);
  pack_w<<<(9*128*144+255)/256, 256, 0, stream>>>(w_k1,  wp_k1,  128, 144, 128, 144);
  pack_w<<<(9*128*128+255)/256, 256, 0, stream>>>(w_k2,  wp_k2,  128, 128, 128, 128);
  pack_w<<<(9*448*128+255)/256, 256, 0, stream>>>(w_k3,  wp_k3,  441, 128, 448, 128);
  pack_bias<<<2, 256, 0, stream>>>(b_k3, bias_k3p, 441, 448);

  // zero both rnn ping-pong buffers (halo borders + step-0 state) and accumulators
  zero_u32<<<2048, 256, 0, stream>>>((unsigned*)rnn_inA, (int)RB);   // RB u32 words = 2*RB elem
  zero_u32<<<2048, 256, 0, stream>>>((unsigned*)rnn_inB, (int)RB);
  zero_u32<<<925,  256, 0, stream>>>((unsigned*)accz, 236678);

  for (int s = 0; s < 8; ++s){
    const float* f   = features + (size_t)s*16*36864;   // batch stride 8*16*36864
    const float* rad = radiance + (size_t)s*3*36864;    // batch stride 8*3*36864
    _Float16* rcur = rnn_buf[s & 1];
    _Float16* rnxt = rnn_buf[(s + 1) & 1];
    // features -> rcur ch0..15 (interior) and k1_in ch128..143 (state arrives via DUAL)
    pack_feat<<<dim3(144,2), 256, 0, stream>>>(f, rcur, k1_in,
                                               8u*16u*36864u, RB, KB);
    // rnn: 144->128 SAME via zero halo, lrelu; -> k1_in ch0..127 AND rnxt halo ch16..143
    // RS: 64-co slices (nco=2), row-split waves, grid 6x48x4 = 1152 blocks
    conv3<144,true ,false,true ,true ,3><<<dim3(6,48,4), 128, 0, stream>>>(
        rcur, 194, RB, wp_rnn, 128, b_rnn, k1_in, 192, 144, KB,
        rnxt, RB, nullptr, 192, 192, 2);
    // k1: 144->128 VALID, lrelu; only window [7,185) (178^2) -> k2_in at (7,7)
    conv3<144,true ,false,false,true ,3><<<dim3(6,45,4), 128, 0, stream>>>(
        k1_in + (size_t)(7*192 + 7)*144, 192, KB, wp_k1, 128, b_k1,
        k2_in + (size_t)(7*190 + 7)*128, 190, 128, K2B,
        nullptr, 0, nullptr, 178, 178, 2);
    // k2: 128->128 VALID, lrelu; only window [7,181) (174^2) -> k3_in at (7,7)
    conv3<128,true ,false,false,true ,3><<<dim3(6,44,4), 128, 0, stream>>>(
        k2_in + (size_t)(7*190 + 7)*128, 190, K2B, wp_k2, 128, b_k2,
        k3_in + (size_t)(7*188 + 7)*128, 188, 128, K3B,
        nullptr, 0, nullptr, 174, 174, 2);
    // k3: 128->441(448 pad, 7 co-slices of 64) VALID, no relu; 172x172 window
    conv3<128,false,true ,false,false,2><<<dim3(6,22,14), 128, 0, stream>>>(
        k3_in + (size_t)(7*188 + 7)*128, 188, K3B, wp_k3, 448, bias_k3p,
        k3_out, 0, 0, KOB, nullptr, 0, slot, 172, 172, 7);
    update_max<<<1, 64, 0, stream>>>(st, slot, s);
    apply_acc<<<dim3(3,43,2), 256, 0, stream>>>(k3_out, rad, st, unnorm, sumw);
  }
  finalize_out<<<dim3(347,2), 256, 0, stream>>>(unnorm, sumw, out);
}